// Round 6
// baseline (317.854 us; speedup 1.0000x reference)
//
#include <hip/hip_runtime.h>
#include <hip/hip_bf16.h>

typedef __attribute__((ext_vector_type(8))) short short8;
typedef __attribute__((ext_vector_type(4))) float float4v;

#define N_NODES 131072
#define E_EDGES 256
#define IN_CH   128
#define OUT_CH  256

// ---------------------------------------------------------------------------
// k1: per-node 256-bit incidence masks + gram nonzero-pattern bitmatrix.
// R6: latency-bound fix. 1024 blocks x 256 threads (4 waves x 32 nodes) ->
// 4 blocks/CU = 16 waves/CU (was 8); float4 H loads (4 instead of 16 loads
// per iter); software-pipelined prefetch of the next node-quad so the ~900cy
// HBM latency hides under the ~600cy ballot/OR block.
// Edge-label permutation note: with float4 loads, ballot of component g gives
// bit L <-> physical edge 4L+g. This permutation is applied consistently to
// masks (word g = ballot g), gram rows (lane L group g owns perm-row g*64+L)
// and gram columns (w[] words) -- and every consumer (popcount, row-OR
// union) is permutation-invariant, so k_gemm is unchanged.
// ---------------------------------------------------------------------------
__global__ __launch_bounds__(256) void k_gram(const float* __restrict__ H,
                                              const float* __restrict__ W,
                                              unsigned long long* __restrict__ masks,
                                              unsigned* __restrict__ gram,
                                              __hip_bfloat16* __restrict__ Wb) {
  if (blockIdx.x == 1024) {  // weight-conversion block
    for (int i = threadIdx.x; i < IN_CH * OUT_CH; i += 256) {
      const int f = i >> 9, lane = (i >> 3) & 63, j = i & 7;
      const int col = (f >> 2) * 16 + (lane & 15);
      const int k = (f & 3) * 32 + (lane >> 4) * 8 + j;
      Wb[i] = __float2bfloat16(W[k * OUT_CH + col]);
    }
    return;
  }

  const int wave = threadIdx.x >> 6;   // 0..3
  const int lane = threadIdx.x & 63;
  const int base = (blockIdx.x * 4 + wave) * 32;  // 32 nodes per wave

  unsigned r[4][8];
#pragma unroll
  for (int g = 0; g < 4; ++g)
#pragma unroll
    for (int j = 0; j < 8; ++j) r[g][j] = 0u;

  const float4* Hv = reinterpret_cast<const float4*>(H);  // row n: Hv[n*64+lane]

  float4 cur[4];
#pragma unroll
  for (int q = 0; q < 4; ++q) cur[q] = Hv[(size_t)(base + q) * 64 + lane];

  for (int it = 0; it < 8; ++it) {     // 4 nodes/iter, prefetched
    const int n0 = base + it * 4;
    float4 nxt[4];
    if (it < 7) {
#pragma unroll
      for (int q = 0; q < 4; ++q) nxt[q] = Hv[(size_t)(n0 + 4 + q) * 64 + lane];
    } else {
#pragma unroll
      for (int q = 0; q < 4; ++q) nxt[q] = cur[q];  // dead value, keeps defined
    }
#pragma unroll
    for (int q = 0; q < 4; ++q) {
      unsigned long long b0 = __ballot(cur[q].x >= 0.5f);
      unsigned long long b1 = __ballot(cur[q].y >= 0.5f);
      unsigned long long b2 = __ballot(cur[q].z >= 0.5f);
      unsigned long long b3 = __ballot(cur[q].w >= 0.5f);
      if (lane < 4)
        masks[(size_t)(n0 + q) * 4 + lane] =
            (lane == 0) ? b0 : (lane == 1) ? b1 : (lane == 2) ? b2 : b3;
      unsigned w[8] = {(unsigned)b0, (unsigned)(b0 >> 32),
                       (unsigned)b1, (unsigned)(b1 >> 32),
                       (unsigned)b2, (unsigned)(b2 >> 32),
                       (unsigned)b3, (unsigned)(b3 >> 32)};
      const unsigned long long bb[4] = {b0, b1, b2, b3};
#pragma unroll
      for (int g = 0; g < 4; ++g) {
        const unsigned sel = ((unsigned)(bb[g] >> lane) & 1u) ? 0xFFFFFFFFu : 0u;
#pragma unroll
        for (int j = 0; j < 8; ++j) r[g][j] |= w[j] & sel;
      }
    }
#pragma unroll
    for (int q = 0; q < 4; ++q) cur[q] = nxt[q];
  }

  __shared__ unsigned gsh[E_EDGES * 8];
  for (int i = threadIdx.x; i < E_EDGES * 8; i += 256) gsh[i] = 0u;
  __syncthreads();
#pragma unroll
  for (int g = 0; g < 4; ++g)
#pragma unroll
    for (int j = 0; j < 8; ++j)
      if (r[g][j]) atomicOr(&gsh[(g * 64 + lane) * 8 + j], r[g][j]);
  __syncthreads();
  for (int i = threadIdx.x; i < E_EDGES * 8; i += 256) {
    unsigned v = gsh[i];
    if (v) {
      // racy pre-read is safe: OR is monotone, stale read only costs an atomic
      unsigned old = gram[i];
      if ((old | v) != old) atomicOr(&gram[i], v);
    }
  }
}

// ---------------------------------------------------------------------------
// k2: fused scale+GEMM, 128 rows x 256 cols per block (1024 blocks x 512
// threads = 8 waves: 2 row-halves x 4 col-strips). Unchanged from R5 (which
// passed at 299.9us) -- this round changes only k_gram for clean attribution.
// ---------------------------------------------------------------------------
__global__ __launch_bounds__(512) void k_gemm(const float* __restrict__ U,
                                              const __hip_bfloat16* __restrict__ Wb,
                                              const unsigned long long* __restrict__ masks,
                                              const unsigned* __restrict__ gram,
                                              const float* __restrict__ bias,
                                              float* __restrict__ out) {
  __shared__ __hip_bfloat16 A[128 * 136];       // 34816 B (136: bank de-alias)
  __shared__ unsigned gsh[E_EDGES * 8];         //  8192 B
  __shared__ unsigned long long msh[128 * 4];   //  4096 B
  __shared__ float ssh[128];
  __shared__ float bsh[OUT_CH];

  const int tid = threadIdx.x;
  const int blockRow = blockIdx.x * 128;

  // stage U tile (128 x 128 fp32) -> bf16 LDS, coalesced float4
  for (int i = tid; i < 128 * 32; i += 512) {
    const int row = i >> 5, c4 = i & 31;
    float4 v = reinterpret_cast<const float4*>(U + (size_t)(blockRow + row) * IN_CH)[c4];
    __hip_bfloat16* dst = &A[row * 136 + c4 * 4];
    dst[0] = __float2bfloat16(v.x);
    dst[1] = __float2bfloat16(v.y);
    dst[2] = __float2bfloat16(v.z);
    dst[3] = __float2bfloat16(v.w);
  }
  // stage gram (512 uint4) + this block's 128 node masks (256 uint4)
  {
    uint4* g4 = reinterpret_cast<uint4*>(gsh);
    const uint4* src = reinterpret_cast<const uint4*>(gram);
    g4[tid] = src[tid];  // 512 threads x 16B = 8192 B exactly
    if (tid < 256) {
      reinterpret_cast<uint4*>(msh)[tid] =
          reinterpret_cast<const uint4*>(masks + (size_t)blockRow * 4)[tid];
      bsh[tid] = bias[tid];
    }
  }
  __syncthreads();

  const int wave = tid >> 6, lane = tid & 63;
  const int quad = lane >> 4, c16 = lane & 15;
  const int wr = wave >> 2, wc = wave & 3;   // row-half, col-strip

  // waves 0 and 4: per-row scale for their 64-row half while others MFMA
  if ((wave & 3) == 0) {
    const int ln = wr * 64 + lane;
    const unsigned long long m0 = msh[ln * 4 + 0];
    const unsigned long long m1 = msh[ln * 4 + 1];
    const unsigned long long m2 = msh[ln * 4 + 2];
    const unsigned long long m3 = msh[ln * 4 + 3];
    int dv = __popcll(m0) + __popcll(m1) + __popcll(m2) + __popcll(m3);
    unsigned o0 = 0, o1 = 0, o2 = 0, o3 = 0, o4 = 0, o5 = 0, o6 = 0, o7 = 0;
    auto scan = [&](unsigned long long bits, int g) -> bool {
      while (bits) {
        int t = __builtin_ctzll(bits);
        bits &= bits - 1;
        const unsigned* gr = &gsh[((g << 6) + t) * 8];
        o0 |= gr[0]; o1 |= gr[1]; o2 |= gr[2]; o3 |= gr[3];
        o4 |= gr[4]; o5 |= gr[5]; o6 |= gr[6]; o7 |= gr[7];
        // saturation early-exit: once the union is all-ones it can't grow
        if ((o0 & o1 & o2 & o3 & o4 & o5 & o6 & o7) == 0xFFFFFFFFu) return true;
      }
      return false;
    };
    (void)(scan(m0, 0) || scan(m1, 1) || scan(m2, 2) || scan(m3, 3));
    dv += __popc(o0) + __popc(o1) + __popc(o2) + __popc(o3) +
          __popc(o4) + __popc(o5) + __popc(o6) + __popc(o7);
    float sv = 1.0f;
    if (dv > 0) sv += 1.0f / sqrtf((float)dv);
    ssh[ln] = sv;
  }

  float4v acc[4][4];
#pragma unroll
  for (int m = 0; m < 4; ++m)
#pragma unroll
    for (int nn = 0; nn < 4; ++nn)
      acc[m][nn] = (float4v){0.f, 0.f, 0.f, 0.f};

#pragma unroll
  for (int ks = 0; ks < 4; ++ks) {
    short8 a[4], b[4];
#pragma unroll
    for (int m = 0; m < 4; ++m)
      a[m] = *reinterpret_cast<const short8*>(
          &A[(wr * 64 + m * 16 + c16) * 136 + ks * 32 + quad * 8]);
#pragma unroll
    for (int nn = 0; nn < 4; ++nn)
      b[nn] = *reinterpret_cast<const short8*>(
          Wb + ((size_t)(((wc * 4 + nn) * 4 + ks) * 64 + lane)) * 8);
#pragma unroll
    for (int m = 0; m < 4; ++m)
#pragma unroll
      for (int nn = 0; nn < 4; ++nn)
        acc[m][nn] = __builtin_amdgcn_mfma_f32_16x16x32_bf16(a[m], b[nn], acc[m][nn], 0, 0, 0);
  }

  __syncthreads();  // ssh ready for all waves

  // epilogue: C/D layout col = lane&15, row = quad*4 + reg
#pragma unroll
  for (int m = 0; m < 4; ++m) {
#pragma unroll
    for (int nn = 0; nn < 4; ++nn) {
      const int col = wc * 64 + nn * 16 + c16;
      const float bv = bsh[col];
#pragma unroll
      for (int rr = 0; rr < 4; ++rr) {
        const int row = wr * 64 + m * 16 + quad * 4 + rr;
        out[(size_t)(blockRow + row) * OUT_CH + col] = ssh[row] * acc[m][nn][rr] + bv;
      }
    }
  }
}

// ---------------------------------------------------------------------------
extern "C" void kernel_launch(void* const* d_in, const int* in_sizes, int n_in,
                              void* d_out, int out_size, void* d_ws, size_t ws_size,
                              hipStream_t stream) {
  const float* H    = (const float*)d_in[0];
  const float* U    = (const float*)d_in[1];
  const float* W    = (const float*)d_in[2];
  const float* bias = (const float*)d_in[3];
  float* out = (float*)d_out;

  // ws layout: gram bitmatrix (8 KiB) | masks (4 MiB) | Wb (64 KiB)
  char* ws = (char*)d_ws;
  unsigned* gram = (unsigned*)ws;
  unsigned long long* masks = (unsigned long long*)(ws + 8192);
  __hip_bfloat16* Wb = (__hip_bfloat16*)(ws + 8192 + (size_t)N_NODES * 32);

  hipMemsetAsync(gram, 0, E_EDGES * 8 * sizeof(unsigned), stream);
  k_gram<<<dim3(1025), dim3(256), 0, stream>>>(H, W, masks, gram, Wb);
  k_gemm<<<dim3(N_NODES / 128), dim3(512), 0, stream>>>(U, Wb, masks, gram, bias, out);
}